// Round 1
// baseline (3776.937 us; speedup 1.0000x reference)
//
#include <hip/hip_runtime.h>
#include <hip/hip_bf16.h>

// SpectralWormhole: 7 bands, LN -> (pair + bridge) sparse cosine top-k attention.
// B=4, T=2048, D=256, NB=7, top_k=16 (fixed by setup_inputs).
// Strategy (round 0, fp32 SIMT baseline):
//   1) ln_kernel: normed[7,B,T,D]
//   2) d_out = bands (d2d copy), then accumulate attention outputs into it
//   3) per attention: proj q/k/v (tiled fp32 GEMM) -> row norms -> sim GEMM
//      (epilogue folds 1/(|q||k|temp)) -> fused topk+softmax+gather -> o-GEMM
//      accumulated into d_out
// Workspace: ~177 MB fp32 scratch.

#define Bv 4
#define Tv 2048
#define Dv 256
#define NBv 7
#define ROWS (Bv * Tv)           // 8192 rows per band
#define BAND ((size_t)ROWS * Dv) // 2,097,152 floats

// ---------------- LayerNorm: one wave per row of 256 ----------------
__global__ __launch_bounds__(256) void ln_kernel(
    const float* __restrict__ x, const float* __restrict__ g,
    const float* __restrict__ bta, float* __restrict__ out) {
  int wid = threadIdx.x >> 6, lane = threadIdx.x & 63;
  int row = blockIdx.x * 4 + wid;          // 0..57343
  int band = row >> 13;                    // row / 8192
  float4 a = ((const float4*)(x + (size_t)row * Dv))[lane];
  float s = a.x + a.y + a.z + a.w;
#pragma unroll
  for (int d = 32; d; d >>= 1) s += __shfl_xor(s, d);
  float m = s * (1.0f / 256.0f);
  float dx = a.x - m, dy = a.y - m, dz = a.z - m, dw = a.w - m;
  float vs = dx * dx + dy * dy + dz * dz + dw * dw;
#pragma unroll
  for (int d = 32; d; d >>= 1) vs += __shfl_xor(vs, d);
  float rstd = 1.0f / sqrtf(vs * (1.0f / 256.0f) + 1e-5f);
  float4 gg = ((const float4*)(g + band * Dv))[lane];
  float4 bb = ((const float4*)(bta + band * Dv))[lane];
  float4 o;
  o.x = dx * rstd * gg.x + bb.x;
  o.y = dy * rstd * gg.y + bb.y;
  o.z = dz * rstd * gg.z + bb.z;
  o.w = dw * rstd * gg.w + bb.w;
  ((float4*)(out + (size_t)row * Dv))[lane] = o;
}

// ---------------- Row L2 norms: one wave per row, two buffers per launch ----
__global__ __launch_bounds__(256) void rownorm_kernel(
    const float* __restrict__ x0, float* __restrict__ o0,
    const float* __restrict__ x1, float* __restrict__ o1) {
  const float* x = blockIdx.y ? x1 : x0;
  float* o = blockIdx.y ? o1 : o0;
  int wid = threadIdx.x >> 6, lane = threadIdx.x & 63;
  int row = blockIdx.x * 4 + wid;
  float4 a = ((const float4*)(x + (size_t)row * Dv))[lane];
  float s = a.x * a.x + a.y * a.y + a.z * a.z + a.w * a.w;
#pragma unroll
  for (int d = 32; d; d >>= 1) s += __shfl_xor(s, d);
  if (lane == 0) o[row] = fmaxf(sqrtf(s), 1e-12f);
}

// ---------------- Projection GEMM: C[8192,256] = alpha*(A@W) + bias (+C) ----
// 64x64 tile, 256 threads, 4x4 micro-tile, BK=16.
__global__ __launch_bounds__(256) void proj_gemm(
    const float* __restrict__ A, const float* __restrict__ W,
    const float* __restrict__ bias, float* __restrict__ C,
    float alpha, int beta) {
  __shared__ float As[16][68];  // [kk][row], padded
  __shared__ float Ws[16][64];  // [kk][col]
  const int tid = threadIdx.x;
  const int tx = tid & 15, ty = tid >> 4;
  const int row0 = blockIdx.y * 64, col0 = blockIdx.x * 64;
  float acc[4][4] = {};
  for (int k0 = 0; k0 < Dv; k0 += 16) {
    {
      int e = tid * 4;
      int r = e >> 4, c = e & 15;  // c in {0,4,8,12}
      float4 v = *(const float4*)(A + (size_t)(row0 + r) * Dv + k0 + c);
      As[c + 0][r] = v.x; As[c + 1][r] = v.y; As[c + 2][r] = v.z; As[c + 3][r] = v.w;
      int r2 = tid >> 4, c2 = (tid & 15) * 4;
      *(float4*)&Ws[r2][c2] = *(const float4*)(W + (size_t)(k0 + r2) * Dv + col0 + c2);
    }
    __syncthreads();
#pragma unroll
    for (int kk = 0; kk < 16; ++kk) {
      float a[4], b[4];
      *(float4*)a = *(const float4*)&As[kk][ty * 4];
      *(float4*)b = *(const float4*)&Ws[kk][tx * 4];
#pragma unroll
      for (int i = 0; i < 4; ++i)
#pragma unroll
        for (int j = 0; j < 4; ++j) acc[i][j] = fmaf(a[i], b[j], acc[i][j]);
    }
    __syncthreads();
  }
  float bj[4];
  *(float4*)bj = *(const float4*)(bias + col0 + tx * 4);
#pragma unroll
  for (int i = 0; i < 4; ++i) {
    size_t off = (size_t)(row0 + ty * 4 + i) * Dv + col0 + tx * 4;
    float4 o;
    o.x = alpha * acc[i][0] + bj[0];
    o.y = alpha * acc[i][1] + bj[1];
    o.z = alpha * acc[i][2] + bj[2];
    o.w = alpha * acc[i][3] + bj[3];
    if (beta) {
      float4 p = *(const float4*)(C + off);
      o.x += p.x; o.y += p.y; o.z += p.z; o.w += p.w;
    }
    *(float4*)(C + off) = o;
  }
}

// ---------------- Sim GEMM (NT): S[b,i,j] = q_i.k_j / (|q_i||k_j|temp) -------
// 128x128 tile, 256 threads, 8x8 micro-tile, BK=16, grid (16,16,4).
__global__ __launch_bounds__(256) void sim_gemm(
    const float* __restrict__ Q, const float* __restrict__ K,
    const float* __restrict__ qn, const float* __restrict__ kn,
    const float* __restrict__ temps, int tidx, float* __restrict__ S) {
  __shared__ float qs[16][132];
  __shared__ float ks[16][132];
  const int tid = threadIdx.x;
  const int tx = tid & 15, ty = tid >> 4;
  const int b = blockIdx.z;
  const int row0 = blockIdx.y * 128, col0 = blockIdx.x * 128;
  const float* Qb = Q + (size_t)b * Tv * Dv;
  const float* Kb = K + (size_t)b * Tv * Dv;
  float acc[8][8] = {};
  for (int k0 = 0; k0 < Dv; k0 += 16) {
#pragma unroll
    for (int h = 0; h < 2; ++h) {
      int e = tid * 4 + h * 1024;
      int r = e >> 4, c = e & 15;
      float4 v = *(const float4*)(Qb + (size_t)(row0 + r) * Dv + k0 + c);
      qs[c + 0][r] = v.x; qs[c + 1][r] = v.y; qs[c + 2][r] = v.z; qs[c + 3][r] = v.w;
      float4 w = *(const float4*)(Kb + (size_t)(col0 + r) * Dv + k0 + c);
      ks[c + 0][r] = w.x; ks[c + 1][r] = w.y; ks[c + 2][r] = w.z; ks[c + 3][r] = w.w;
    }
    __syncthreads();
#pragma unroll
    for (int kk = 0; kk < 16; ++kk) {
      float a[8], bb[8];
      *(float4*)&a[0] = *(const float4*)&qs[kk][ty * 8];
      *(float4*)&a[4] = *(const float4*)&qs[kk][ty * 8 + 4];
      *(float4*)&bb[0] = *(const float4*)&ks[kk][tx * 8];
      *(float4*)&bb[4] = *(const float4*)&ks[kk][tx * 8 + 4];
#pragma unroll
      for (int i = 0; i < 8; ++i)
#pragma unroll
        for (int j = 0; j < 8; ++j) acc[i][j] = fmaf(a[i], bb[j], acc[i][j]);
    }
    __syncthreads();
  }
  float temp = temps[tidx];
  float rs[8], cs[8];
#pragma unroll
  for (int i = 0; i < 8; ++i) rs[i] = 1.0f / (qn[b * Tv + row0 + ty * 8 + i] * temp);
#pragma unroll
  for (int j = 0; j < 8; ++j) cs[j] = 1.0f / kn[b * Tv + col0 + tx * 8 + j];
#pragma unroll
  for (int i = 0; i < 8; ++i) {
    size_t off = ((size_t)b * Tv + row0 + ty * 8 + i) * Tv + col0 + tx * 8;
    float4 o0, o1;
    o0.x = acc[i][0] * rs[i] * cs[0]; o0.y = acc[i][1] * rs[i] * cs[1];
    o0.z = acc[i][2] * rs[i] * cs[2]; o0.w = acc[i][3] * rs[i] * cs[3];
    o1.x = acc[i][4] * rs[i] * cs[4]; o1.y = acc[i][5] * rs[i] * cs[5];
    o1.z = acc[i][6] * rs[i] * cs[6]; o1.w = acc[i][7] * rs[i] * cs[7];
    *(float4*)(S + off) = o0;
    *(float4*)(S + off + 4) = o1;
  }
}

// ---------------- Fused top-16 + softmax + weighted V gather ----------------
// One block (256 threads) per query row; sim row lives in registers (8/thread).
__global__ __launch_bounds__(256) void topk_gather(
    const float* __restrict__ S, const float* __restrict__ V,
    float* __restrict__ out, int accumulate) {
  const int tid = threadIdx.x;
  const int r = blockIdx.x;  // 0..8191 (b*T + i)
  const float* srow = S + (size_t)r * Tv;
  float v8[8];
  const int base = tid * 8;
  *(float4*)&v8[0] = *(const float4*)(srow + base);
  *(float4*)&v8[4] = *(const float4*)(srow + base + 4);
  __shared__ float swv[4];
  __shared__ int swi[4];
  __shared__ float topv[16];
  __shared__ int topi[16];
  __shared__ float wexp[16];
  const int wid = tid >> 6, lane = tid & 63;
  for (int it = 0; it < 16; ++it) {
    float bv = v8[0];
    int bi = 0;
#pragma unroll
    for (int s2 = 1; s2 < 8; ++s2)
      if (v8[s2] > bv) { bv = v8[s2]; bi = s2; }
    int gi = base + bi;
#pragma unroll
    for (int d = 32; d; d >>= 1) {
      float ov = __shfl_xor(bv, d);
      int oi = __shfl_xor(gi, d);
      if (ov > bv || (ov == bv && oi < gi)) { bv = ov; gi = oi; }
    }
    if (lane == 0) { swv[wid] = bv; swi[wid] = gi; }
    __syncthreads();
    if (tid == 0) {
      float m = swv[0]; int mi = swi[0];
      for (int w2 = 1; w2 < 4; ++w2)
        if (swv[w2] > m || (swv[w2] == m && swi[w2] < mi)) { m = swv[w2]; mi = swi[w2]; }
      topv[it] = m; topi[it] = mi;
    }
    __syncthreads();
    int widx = topi[it];
    if (widx >= base && widx < base + 8) v8[widx - base] = -3.0e38f;
  }
  if (tid < 16) wexp[tid] = __expf(topv[tid] - topv[0]);
  __syncthreads();
  float ssum = 0.f;
#pragma unroll
  for (int j = 0; j < 16; ++j) ssum += wexp[j];
  float inv = 1.0f / ssum;
  const float* Vb = V + ((size_t)(r >> 11) << 11) * Dv;  // batch base
  float o = 0.f;
#pragma unroll
  for (int j = 0; j < 16; ++j) o += wexp[j] * Vb[(size_t)topi[j] * Dv + tid];
  o *= inv;
  size_t oidx = (size_t)r * Dv + tid;
  if (accumulate) out[oidx] += o;
  else out[oidx] = o;
}

extern "C" void kernel_launch(void* const* d_in, const int* in_sizes, int n_in,
                              void* d_out, int out_size, void* d_ws, size_t ws_size,
                              hipStream_t stream) {
  const float* bands = (const float*)d_in[0];
  const float* pair_qW = (const float*)d_in[1];
  const float* pair_qb = (const float*)d_in[2];
  const float* pair_kW = (const float*)d_in[3];
  const float* pair_kb = (const float*)d_in[4];
  const float* pair_vW = (const float*)d_in[5];
  const float* pair_vb = (const float*)d_in[6];
  const float* pair_oW = (const float*)d_in[7];
  const float* pair_ob = (const float*)d_in[8];
  const float* bridge_qW = (const float*)d_in[9];
  const float* bridge_qb = (const float*)d_in[10];
  const float* bridge_kW = (const float*)d_in[11];
  const float* bridge_kb = (const float*)d_in[12];
  const float* bridge_vW = (const float*)d_in[13];
  const float* bridge_vb = (const float*)d_in[14];
  const float* bridge_oW = (const float*)d_in[15];
  const float* bridge_ob = (const float*)d_in[16];
  const float* temps = (const float*)d_in[17];
  const float* ln_g = (const float*)d_in[18];
  const float* ln_b = (const float*)d_in[19];
  // top_k fixed at 16 (d_in[20])

  float* out = (float*)d_out;
  float* ws = (float*)d_ws;

  float* normed = ws;                       // 7*BAND
  float* qbuf = normed + NBv * BAND;        // BAND
  float* kbuf = qbuf + BAND;                // BAND
  float* vbuf = kbuf + BAND;                // BAND
  float* simb = vbuf + BAND;                // B*T*T = 16,777,216
  float* wbuf = simb + (size_t)Bv * Tv * Tv;  // BAND
  float* accb = wbuf + BAND;                // BAND
  float* qbr = accb + BAND;                 // BAND
  float* qn = qbr + BAND;                   // 8192
  float* kn = qn + ROWS;                    // 8192
  float* qbn = kn + ROWS;                   // 8192

  static const int SRC[6] = {0, 6, 1, 5, 2, 4};
  static const int DST[6] = {6, 0, 5, 1, 4, 2};
  static const int OTHERS[6] = {0, 1, 2, 4, 5, 6};

  // out = bands
  hipMemcpyAsync(out, bands, sizeof(float) * NBv * BAND, hipMemcpyDeviceToDevice, stream);
  // normed = LN(bands)
  ln_kernel<<<NBv * ROWS / 4, 256, 0, stream>>>(bands, ln_g, ln_b, normed);

  const dim3 pgrid(Dv / 64, ROWS / 64);    // (4,128)
  const dim3 sgrid(Tv / 128, Tv / 128, Bv);  // (16,16,4)

  // ---- pair attentions ----
  for (int p = 0; p < 6; ++p) {
    const float* An = normed + (size_t)SRC[p] * BAND;
    const float* Ad = normed + (size_t)DST[p] * BAND;
    proj_gemm<<<pgrid, 256, 0, stream>>>(An, pair_qW + (size_t)p * 65536, pair_qb + p * 256, qbuf, 1.f, 0);
    proj_gemm<<<pgrid, 256, 0, stream>>>(Ad, pair_kW + (size_t)p * 65536, pair_kb + p * 256, kbuf, 1.f, 0);
    proj_gemm<<<pgrid, 256, 0, stream>>>(Ad, pair_vW + (size_t)p * 65536, pair_vb + p * 256, vbuf, 1.f, 0);
    rownorm_kernel<<<dim3(ROWS / 4, 2), 256, 0, stream>>>(qbuf, qn, kbuf, kn);
    sim_gemm<<<sgrid, 256, 0, stream>>>(qbuf, kbuf, qn, kn, temps, p, simb);
    topk_gather<<<ROWS, 256, 0, stream>>>(simb, vbuf, wbuf, 0);
    proj_gemm<<<pgrid, 256, 0, stream>>>(wbuf, pair_oW + (size_t)p * 65536, pair_ob + p * 256,
                                         out + (size_t)SRC[p] * BAND, 1.f, 1);
  }

  // ---- bridge ----
  proj_gemm<<<pgrid, 256, 0, stream>>>(normed + 3 * BAND, bridge_qW, bridge_qb, qbr, 1.f, 0);
  rownorm_kernel<<<dim3(ROWS / 4, 1), 256, 0, stream>>>(qbr, qbn, qbr, qbn);
  hipMemsetAsync(accb, 0, sizeof(float) * BAND, stream);
  for (int i = 0; i < 6; ++i) {
    const float* Ao = normed + (size_t)OTHERS[i] * BAND;
    proj_gemm<<<pgrid, 256, 0, stream>>>(Ao, bridge_kW + (size_t)i * 65536, bridge_kb + i * 256, kbuf, 1.f, 0);
    proj_gemm<<<pgrid, 256, 0, stream>>>(Ao, bridge_vW + (size_t)i * 65536, bridge_vb + i * 256, vbuf, 1.f, 0);
    rownorm_kernel<<<dim3(ROWS / 4, 1), 256, 0, stream>>>(kbuf, kn, kbuf, kn);
    sim_gemm<<<sgrid, 256, 0, stream>>>(qbr, kbuf, qbn, kn, temps, 6, simb);
    topk_gather<<<ROWS, 256, 0, stream>>>(simb, vbuf, accb, 1);
  }
  proj_gemm<<<pgrid, 256, 0, stream>>>(accb, bridge_oW, bridge_ob, out + 3 * BAND,
                                       1.0f / 6.0f, 1);
}

// Round 2
// 3082.945 us; speedup vs baseline: 1.2251x; 1.2251x over previous
//
#include <hip/hip_runtime.h>
#include <hip/hip_bf16.h>

// SpectralWormhole: 7 bands, LN -> (pair + bridge) sparse cosine top-k attention.
// B=4, T=2048, D=256, NB=7, top_k=16 (fixed by setup_inputs).
// Round 1: topk_gather rewritten as one-wave-per-row, barrier-free extraction
// on packed u64 sortable keys (value<<32 | (2047-col)). No LDS, no syncthreads.
// GEMMs unchanged (fp32 SIMT); bf16x3 MFMA planned next.

#define Bv 4
#define Tv 2048
#define Dv 256
#define NBv 7
#define ROWS (Bv * Tv)           // 8192 rows per band
#define BAND ((size_t)ROWS * Dv) // 2,097,152 floats

// ---------------- LayerNorm: one wave per row of 256 ----------------
__global__ __launch_bounds__(256) void ln_kernel(
    const float* __restrict__ x, const float* __restrict__ g,
    const float* __restrict__ bta, float* __restrict__ out) {
  int wid = threadIdx.x >> 6, lane = threadIdx.x & 63;
  int row = blockIdx.x * 4 + wid;          // 0..57343
  int band = row >> 13;                    // row / 8192
  float4 a = ((const float4*)(x + (size_t)row * Dv))[lane];
  float s = a.x + a.y + a.z + a.w;
#pragma unroll
  for (int d = 32; d; d >>= 1) s += __shfl_xor(s, d);
  float m = s * (1.0f / 256.0f);
  float dx = a.x - m, dy = a.y - m, dz = a.z - m, dw = a.w - m;
  float vs = dx * dx + dy * dy + dz * dz + dw * dw;
#pragma unroll
  for (int d = 32; d; d >>= 1) vs += __shfl_xor(vs, d);
  float rstd = 1.0f / sqrtf(vs * (1.0f / 256.0f) + 1e-5f);
  float4 gg = ((const float4*)(g + band * Dv))[lane];
  float4 bb = ((const float4*)(bta + band * Dv))[lane];
  float4 o;
  o.x = dx * rstd * gg.x + bb.x;
  o.y = dy * rstd * gg.y + bb.y;
  o.z = dz * rstd * gg.z + bb.z;
  o.w = dw * rstd * gg.w + bb.w;
  ((float4*)(out + (size_t)row * Dv))[lane] = o;
}

// ---------------- Row L2 norms: one wave per row, two buffers per launch ----
__global__ __launch_bounds__(256) void rownorm_kernel(
    const float* __restrict__ x0, float* __restrict__ o0,
    const float* __restrict__ x1, float* __restrict__ o1) {
  const float* x = blockIdx.y ? x1 : x0;
  float* o = blockIdx.y ? o1 : o0;
  int wid = threadIdx.x >> 6, lane = threadIdx.x & 63;
  int row = blockIdx.x * 4 + wid;
  float4 a = ((const float4*)(x + (size_t)row * Dv))[lane];
  float s = a.x * a.x + a.y * a.y + a.z * a.z + a.w * a.w;
#pragma unroll
  for (int d = 32; d; d >>= 1) s += __shfl_xor(s, d);
  if (lane == 0) o[row] = fmaxf(sqrtf(s), 1e-12f);
}

// ---------------- Projection GEMM: C[8192,256] = alpha*(A@W) + bias (+C) ----
// 64x64 tile, 256 threads, 4x4 micro-tile, BK=16.
__global__ __launch_bounds__(256) void proj_gemm(
    const float* __restrict__ A, const float* __restrict__ W,
    const float* __restrict__ bias, float* __restrict__ C,
    float alpha, int beta) {
  __shared__ float As[16][68];  // [kk][row], padded
  __shared__ float Ws[16][64];  // [kk][col]
  const int tid = threadIdx.x;
  const int tx = tid & 15, ty = tid >> 4;
  const int row0 = blockIdx.y * 64, col0 = blockIdx.x * 64;
  float acc[4][4] = {};
  for (int k0 = 0; k0 < Dv; k0 += 16) {
    {
      int e = tid * 4;
      int r = e >> 4, c = e & 15;  // c in {0,4,8,12}
      float4 v = *(const float4*)(A + (size_t)(row0 + r) * Dv + k0 + c);
      As[c + 0][r] = v.x; As[c + 1][r] = v.y; As[c + 2][r] = v.z; As[c + 3][r] = v.w;
      int r2 = tid >> 4, c2 = (tid & 15) * 4;
      *(float4*)&Ws[r2][c2] = *(const float4*)(W + (size_t)(k0 + r2) * Dv + col0 + c2);
    }
    __syncthreads();
#pragma unroll
    for (int kk = 0; kk < 16; ++kk) {
      float a[4], b[4];
      *(float4*)a = *(const float4*)&As[kk][ty * 4];
      *(float4*)b = *(const float4*)&Ws[kk][tx * 4];
#pragma unroll
      for (int i = 0; i < 4; ++i)
#pragma unroll
        for (int j = 0; j < 4; ++j) acc[i][j] = fmaf(a[i], b[j], acc[i][j]);
    }
    __syncthreads();
  }
  float bj[4];
  *(float4*)bj = *(const float4*)(bias + col0 + tx * 4);
#pragma unroll
  for (int i = 0; i < 4; ++i) {
    size_t off = (size_t)(row0 + ty * 4 + i) * Dv + col0 + tx * 4;
    float4 o;
    o.x = alpha * acc[i][0] + bj[0];
    o.y = alpha * acc[i][1] + bj[1];
    o.z = alpha * acc[i][2] + bj[2];
    o.w = alpha * acc[i][3] + bj[3];
    if (beta) {
      float4 p = *(const float4*)(C + off);
      o.x += p.x; o.y += p.y; o.z += p.z; o.w += p.w;
    }
    *(float4*)(C + off) = o;
  }
}

// ---------------- Sim GEMM (NT): S[b,i,j] = q_i.k_j / (|q_i||k_j|temp) -------
// 128x128 tile, 256 threads, 8x8 micro-tile, BK=16, grid (16,16,4).
__global__ __launch_bounds__(256) void sim_gemm(
    const float* __restrict__ Q, const float* __restrict__ K,
    const float* __restrict__ qn, const float* __restrict__ kn,
    const float* __restrict__ temps, int tidx, float* __restrict__ S) {
  __shared__ float qs[16][132];
  __shared__ float ks[16][132];
  const int tid = threadIdx.x;
  const int tx = tid & 15, ty = tid >> 4;
  const int b = blockIdx.z;
  const int row0 = blockIdx.y * 128, col0 = blockIdx.x * 128;
  const float* Qb = Q + (size_t)b * Tv * Dv;
  const float* Kb = K + (size_t)b * Tv * Dv;
  float acc[8][8] = {};
  for (int k0 = 0; k0 < Dv; k0 += 16) {
#pragma unroll
    for (int h = 0; h < 2; ++h) {
      int e = tid * 4 + h * 1024;
      int r = e >> 4, c = e & 15;
      float4 v = *(const float4*)(Qb + (size_t)(row0 + r) * Dv + k0 + c);
      qs[c + 0][r] = v.x; qs[c + 1][r] = v.y; qs[c + 2][r] = v.z; qs[c + 3][r] = v.w;
      float4 w = *(const float4*)(Kb + (size_t)(col0 + r) * Dv + k0 + c);
      ks[c + 0][r] = w.x; ks[c + 1][r] = w.y; ks[c + 2][r] = w.z; ks[c + 3][r] = w.w;
    }
    __syncthreads();
#pragma unroll
    for (int kk = 0; kk < 16; ++kk) {
      float a[8], bb[8];
      *(float4*)&a[0] = *(const float4*)&qs[kk][ty * 8];
      *(float4*)&a[4] = *(const float4*)&qs[kk][ty * 8 + 4];
      *(float4*)&bb[0] = *(const float4*)&ks[kk][tx * 8];
      *(float4*)&bb[4] = *(const float4*)&ks[kk][tx * 8 + 4];
#pragma unroll
      for (int i = 0; i < 8; ++i)
#pragma unroll
        for (int j = 0; j < 8; ++j) acc[i][j] = fmaf(a[i], bb[j], acc[i][j]);
    }
    __syncthreads();
  }
  float temp = temps[tidx];
  float rs[8], cs[8];
#pragma unroll
  for (int i = 0; i < 8; ++i) rs[i] = 1.0f / (qn[b * Tv + row0 + ty * 8 + i] * temp);
#pragma unroll
  for (int j = 0; j < 8; ++j) cs[j] = 1.0f / kn[b * Tv + col0 + tx * 8 + j];
#pragma unroll
  for (int i = 0; i < 8; ++i) {
    size_t off = ((size_t)b * Tv + row0 + ty * 8 + i) * Tv + col0 + tx * 8;
    float4 o0, o1;
    o0.x = acc[i][0] * rs[i] * cs[0]; o0.y = acc[i][1] * rs[i] * cs[1];
    o0.z = acc[i][2] * rs[i] * cs[2]; o0.w = acc[i][3] * rs[i] * cs[3];
    o1.x = acc[i][4] * rs[i] * cs[4]; o1.y = acc[i][5] * rs[i] * cs[5];
    o1.z = acc[i][6] * rs[i] * cs[6]; o1.w = acc[i][7] * rs[i] * cs[7];
    *(float4*)(S + off) = o0;
    *(float4*)(S + off + 4) = o1;
  }
}

// ---------------- Fused top-16 + softmax + weighted V gather ----------------
// One WAVE per query row. No LDS, no barriers. Each lane holds 32 sim values
// packed as u64 sortable keys: (sortable_u32(val) << 32) | (2047 - col).
// Larger key == larger value, ties broken toward LOWER col (matches lax.top_k).
// Extraction: 16x [64-lane butterfly max of lane-bests; owner rescans its 32
// keys under strict (< winner) ceiling -- provably excludes prior winners].
__global__ __launch_bounds__(256) void topk_gather(
    const float* __restrict__ S, const float* __restrict__ V,
    float* __restrict__ out, int accumulate) {
  const int lane = threadIdx.x & 63;
  const int wid = threadIdx.x >> 6;
  const int r = blockIdx.x * 4 + wid;  // 0..8191 (b*T + i)
  const float* srow = S + (size_t)r * Tv;

  unsigned long long key[32];
#pragma unroll
  for (int j = 0; j < 8; ++j) {
    float4 v = *(const float4*)(srow + j * 256 + lane * 4);
    float vv[4] = {v.x, v.y, v.z, v.w};
#pragma unroll
    for (int c = 0; c < 4; ++c) {
      unsigned u = __float_as_uint(vv[c]);
      unsigned su = u ^ ((unsigned)(((int)u) >> 31) | 0x80000000u);
      int col = j * 256 + lane * 4 + c;
      key[j * 4 + c] =
          ((unsigned long long)su << 32) | (unsigned)(2047 - col);
    }
  }
  // local best of 32
  unsigned long long best = key[0];
#pragma unroll
  for (int s = 1; s < 32; ++s) best = key[s] > best ? key[s] : best;

  unsigned long long wkey[16];
#pragma unroll
  for (int it = 0; it < 16; ++it) {
    unsigned long long m = best;
#pragma unroll
    for (int d = 32; d; d >>= 1) {
      unsigned long long o = __shfl_xor(m, d);
      m = o > m ? o : m;
    }
    wkey[it] = m;  // every lane records the winner
    if (best == m) {
      // this lane owned the winner: recompute best under ceiling (< m).
      // All remaining keys of this lane are < m; prior winners are > m.
      unsigned long long nb = 0ull;
#pragma unroll
      for (int s = 0; s < 32; ++s) {
        unsigned long long k2 = key[s] < m ? key[s] : 0ull;
        nb = k2 > nb ? k2 : nb;
      }
      best = nb;
    }
  }

  // decode values + softmax (wkey[0] is the max)
  float w[16];
#pragma unroll
  for (int it = 0; it < 16; ++it) {
    unsigned su = (unsigned)(wkey[it] >> 32);
    unsigned m2 = (unsigned)((~(int)su) >> 31) | 0x80000000u;
    w[it] = __uint_as_float(su ^ m2);
  }
  float ssum = 0.f;
#pragma unroll
  for (int it = 0; it < 16; ++it) {
    w[it] = __expf(w[it] - w[0]);
    ssum += w[it];
  }
  const float inv = 1.0f / ssum;

  // weighted gather of V rows; lane handles 4 of 256 dims (coalesced per j)
  const float* Vb = V + ((size_t)(r >> 11) << 11) * Dv;  // batch base
  float4 acc = {0.f, 0.f, 0.f, 0.f};
#pragma unroll
  for (int it = 0; it < 16; ++it) {
    int col = 2047 - (int)(wkey[it] & 0x7FFu);
    float4 vv = *(const float4*)(Vb + (size_t)col * Dv + lane * 4);
    acc.x += w[it] * vv.x;
    acc.y += w[it] * vv.y;
    acc.z += w[it] * vv.z;
    acc.w += w[it] * vv.w;
  }
  acc.x *= inv; acc.y *= inv; acc.z *= inv; acc.w *= inv;

  float* op = out + (size_t)r * Dv + lane * 4;
  if (accumulate) {
    float4 p = *(const float4*)op;
    acc.x += p.x; acc.y += p.y; acc.z += p.z; acc.w += p.w;
  }
  *(float4*)op = acc;
}

extern "C" void kernel_launch(void* const* d_in, const int* in_sizes, int n_in,
                              void* d_out, int out_size, void* d_ws, size_t ws_size,
                              hipStream_t stream) {
  const float* bands = (const float*)d_in[0];
  const float* pair_qW = (const float*)d_in[1];
  const float* pair_qb = (const float*)d_in[2];
  const float* pair_kW = (const float*)d_in[3];
  const float* pair_kb = (const float*)d_in[4];
  const float* pair_vW = (const float*)d_in[5];
  const float* pair_vb = (const float*)d_in[6];
  const float* pair_oW = (const float*)d_in[7];
  const float* pair_ob = (const float*)d_in[8];
  const float* bridge_qW = (const float*)d_in[9];
  const float* bridge_qb = (const float*)d_in[10];
  const float* bridge_kW = (const float*)d_in[11];
  const float* bridge_kb = (const float*)d_in[12];
  const float* bridge_vW = (const float*)d_in[13];
  const float* bridge_vb = (const float*)d_in[14];
  const float* bridge_oW = (const float*)d_in[15];
  const float* bridge_ob = (const float*)d_in[16];
  const float* temps = (const float*)d_in[17];
  const float* ln_g = (const float*)d_in[18];
  const float* ln_b = (const float*)d_in[19];
  // top_k fixed at 16 (d_in[20])

  float* out = (float*)d_out;
  float* ws = (float*)d_ws;

  float* normed = ws;                       // 7*BAND
  float* qbuf = normed + NBv * BAND;        // BAND
  float* kbuf = qbuf + BAND;                // BAND
  float* vbuf = kbuf + BAND;                // BAND
  float* simb = vbuf + BAND;                // B*T*T = 16,777,216
  float* wbuf = simb + (size_t)Bv * Tv * Tv;  // BAND
  float* accb = wbuf + BAND;                // BAND
  float* qbr = accb + BAND;                 // BAND
  float* qn = qbr + BAND;                   // 8192
  float* kn = qn + ROWS;                    // 8192
  float* qbn = kn + ROWS;                   // 8192

  static const int SRC[6] = {0, 6, 1, 5, 2, 4};
  static const int DST[6] = {6, 0, 5, 1, 4, 2};
  static const int OTHERS[6] = {0, 1, 2, 4, 5, 6};

  // out = bands
  hipMemcpyAsync(out, bands, sizeof(float) * NBv * BAND, hipMemcpyDeviceToDevice, stream);
  // normed = LN(bands)
  ln_kernel<<<NBv * ROWS / 4, 256, 0, stream>>>(bands, ln_g, ln_b, normed);

  const dim3 pgrid(Dv / 64, ROWS / 64);    // (4,128)
  const dim3 sgrid(Tv / 128, Tv / 128, Bv);  // (16,16,4)

  // ---- pair attentions ----
  for (int p = 0; p < 6; ++p) {
    const float* An = normed + (size_t)SRC[p] * BAND;
    const float* Ad = normed + (size_t)DST[p] * BAND;
    proj_gemm<<<pgrid, 256, 0, stream>>>(An, pair_qW + (size_t)p * 65536, pair_qb + p * 256, qbuf, 1.f, 0);
    proj_gemm<<<pgrid, 256, 0, stream>>>(Ad, pair_kW + (size_t)p * 65536, pair_kb + p * 256, kbuf, 1.f, 0);
    proj_gemm<<<pgrid, 256, 0, stream>>>(Ad, pair_vW + (size_t)p * 65536, pair_vb + p * 256, vbuf, 1.f, 0);
    rownorm_kernel<<<dim3(ROWS / 4, 2), 256, 0, stream>>>(qbuf, qn, kbuf, kn);
    sim_gemm<<<sgrid, 256, 0, stream>>>(qbuf, kbuf, qn, kn, temps, p, simb);
    topk_gather<<<ROWS / 4, 256, 0, stream>>>(simb, vbuf, wbuf, 0);
    proj_gemm<<<pgrid, 256, 0, stream>>>(wbuf, pair_oW + (size_t)p * 65536, pair_ob + p * 256,
                                         out + (size_t)SRC[p] * BAND, 1.f, 1);
  }

  // ---- bridge ----
  proj_gemm<<<pgrid, 256, 0, stream>>>(normed + 3 * BAND, bridge_qW, bridge_qb, qbr, 1.f, 0);
  rownorm_kernel<<<dim3(ROWS / 4, 1), 256, 0, stream>>>(qbr, qbn, qbr, qbn);
  hipMemsetAsync(accb, 0, sizeof(float) * BAND, stream);
  for (int i = 0; i < 6; ++i) {
    const float* Ao = normed + (size_t)OTHERS[i] * BAND;
    proj_gemm<<<pgrid, 256, 0, stream>>>(Ao, bridge_kW + (size_t)i * 65536, bridge_kb + i * 256, kbuf, 1.f, 0);
    proj_gemm<<<pgrid, 256, 0, stream>>>(Ao, bridge_vW + (size_t)i * 65536, bridge_vb + i * 256, vbuf, 1.f, 0);
    rownorm_kernel<<<dim3(ROWS / 4, 1), 256, 0, stream>>>(kbuf, kn, kbuf, kn);
    sim_gemm<<<sgrid, 256, 0, stream>>>(qbr, kbuf, qbn, kn, temps, 6, simb);
    topk_gather<<<ROWS / 4, 256, 0, stream>>>(simb, vbuf, accb, 1);
  }
  proj_gemm<<<pgrid, 256, 0, stream>>>(accb, bridge_oW, bridge_ob, out + 3 * BAND,
                                       1.0f / 6.0f, 1);
}

// Round 4
// 2180.979 us; speedup vs baseline: 1.7318x; 1.4136x over previous
//
#include <hip/hip_runtime.h>
#include <hip/hip_bf16.h>

// SpectralWormhole: 7 bands, LN -> (pair + bridge) sparse cosine top-k attention.
// B=4, T=2048, D=256, NB=7, top_k=16.
// Round 3 (= round 2 resubmit; GPU acquisition timed out, kernel never ran):
// ALL GEMMs on matrix cores via fp16 hi/lo split (3-segment MFMA,
// fp32-grade precision). Operands stored as 2 fp16 planes {hi, lo*512}; the
// 2^-9 counter-scale is applied to the OTHER operand's hi during LDS staging
// (exact exponent shifts; avoids fp16 subnormals).
//   seg0: hi_a * hi_b;  seg1: (hi_a*2^-9) * lo_s_b;  seg2: lo_s_a * (hi_b*2^-9)
// One NT MFMA kernel (A[M,K] x B[N,K]^T), templated tile + epilogue mode:
//   MODE 0 = sim (scale by 1/(|q||k|temp), fp32 out)
//   MODE 1 = proj fp32 (+bias)           (v projection)
//   MODE 2 = proj -> hi/lo planes (+bias) (q,k projections, feeds sim)
//   MODE 3 = proj accumulate (+alpha,+bias) into fp32 (o projections)
// topk_gather: round-1 wave-per-row u64-key version, plus an HL-output mode
// so attention outputs feed the o-projection directly.

#define Bv 4
#define Tv 2048
#define Dv 256
#define NBv 7
#define ROWS (Bv * Tv)            // 8192 rows per band
#define BANDF ((size_t)ROWS * Dv) // 2,097,152 elements

typedef _Float16 h16;
typedef _Float16 h8 __attribute__((ext_vector_type(8)));
typedef _Float16 h4 __attribute__((ext_vector_type(4)));
typedef float f4 __attribute__((ext_vector_type(4)));

__device__ __forceinline__ void split_hl(float y, h16& hi, h16& los) {
  hi = (h16)y;
  float lo = y - (float)hi;        // exact (Sterbenz)
  los = (h16)(lo * 512.0f);        // keep residual in fp16 normal range
}

// ---------------- LayerNorm -> hi/lo planes. One wave per row of 256 -------
__global__ __launch_bounds__(256) void ln_hl(
    const float* __restrict__ x, const float* __restrict__ g,
    const float* __restrict__ bta, h16* __restrict__ nhl) {
  int wid = threadIdx.x >> 6, lane = threadIdx.x & 63;
  int row = blockIdx.x * 4 + wid;          // 0..57343
  int band = row >> 13, rowin = row & 8191;
  float4 a = ((const float4*)(x + (size_t)row * Dv))[lane];
  float s = a.x + a.y + a.z + a.w;
#pragma unroll
  for (int d = 32; d; d >>= 1) s += __shfl_xor(s, d);
  float m = s * (1.0f / 256.0f);
  float dx = a.x - m, dy = a.y - m, dz = a.z - m, dw = a.w - m;
  float vs = dx * dx + dy * dy + dz * dz + dw * dw;
#pragma unroll
  for (int d = 32; d; d >>= 1) vs += __shfl_xor(vs, d);
  float rstd = 1.0f / sqrtf(vs * (1.0f / 256.0f) + 1e-5f);
  float4 gg = ((const float4*)(g + band * Dv))[lane];
  float4 bb = ((const float4*)(bta + band * Dv))[lane];
  float o[4] = {dx * rstd * gg.x + bb.x, dy * rstd * gg.y + bb.y,
                dz * rstd * gg.z + bb.z, dw * rstd * gg.w + bb.w};
  h4 hv, lv;
#pragma unroll
  for (int i = 0; i < 4; ++i) { h16 hi, lo; split_hl(o[i], hi, lo); hv[i] = hi; lv[i] = lo; }
  h16* base = nhl + (size_t)band * (2 * BANDF) + (size_t)rowin * Dv + lane * 4;
  *(h4*)base = hv;
  *(h4*)(base + BANDF) = lv;
}

// ---------------- Weight transpose + split: all 38 [256,256] mats ----------
// wt layout: mat m -> [hi[256n][256k], lo[256n][256k]] at wt + m*131072.
// mats 0-5 pair_qW, 6-11 pair_kW, 12-17 pair_vW, 18-23 pair_oW,
// 24-29 bridge_kW, 30-35 bridge_vW, 36 bridge_qW, 37 bridge_oW.
__global__ __launch_bounds__(256) void wtrans_all(
    const float* __restrict__ qW, const float* __restrict__ kW,
    const float* __restrict__ vW, const float* __restrict__ oW,
    const float* __restrict__ bkW, const float* __restrict__ bvW,
    const float* __restrict__ bqW, const float* __restrict__ boW,
    h16* __restrict__ wt) {
  int mat = blockIdx.x >> 6;
  int lb = blockIdx.x & 63;
  const float* src; int rel;
  if (mat < 6)        { src = qW;  rel = mat; }
  else if (mat < 12)  { src = kW;  rel = mat - 6; }
  else if (mat < 18)  { src = vW;  rel = mat - 12; }
  else if (mat < 24)  { src = oW;  rel = mat - 18; }
  else if (mat < 30)  { src = bkW; rel = mat - 24; }
  else if (mat < 36)  { src = bvW; rel = mat - 30; }
  else if (mat == 36) { src = bqW; rel = 0; }
  else                { src = boW; rel = 0; }
  src += (size_t)rel * 65536;
  h16* dhi = wt + (size_t)mat * 131072;
  h16* dlo = dhi + 65536;
  int t = lb * 256 + threadIdx.x;    // 0..16383
  int n = t >> 6, k4 = (t & 63) * 4;
  h4 hv, lv;
#pragma unroll
  for (int i = 0; i < 4; ++i) {
    float x = src[(size_t)(k4 + i) * 256 + n];  // W[k][n]
    h16 hi, lo; split_hl(x, hi, lo);
    hv[i] = hi; lv[i] = lo;
  }
  *(h4*)(dhi + (size_t)n * 256 + k4) = hv;      // Wt[n][k]
  *(h4*)(dlo + (size_t)n * 256 + k4) = lv;
}

// ---------------- Row L2 norms from hi/lo planes (plane stride = BANDF) ----
__global__ __launch_bounds__(256) void rownorm_hl(
    const h16* __restrict__ x0, float* __restrict__ o0,
    const h16* __restrict__ x1, float* __restrict__ o1) {
  const h16* x = blockIdx.y ? x1 : x0;
  float* o = blockIdx.y ? o1 : o0;
  int wid = threadIdx.x >> 6, lane = threadIdx.x & 63;
  int row = blockIdx.x * 4 + wid;
  h4 hi = *(const h4*)(x + (size_t)row * Dv + lane * 4);
  h4 lo = *(const h4*)(x + BANDF + (size_t)row * Dv + lane * 4);
  float s = 0.f;
#pragma unroll
  for (int i = 0; i < 4; ++i) {
    float v = (float)hi[i] + (float)lo[i] * (1.0f / 512.0f);
    s += v * v;
  }
#pragma unroll
  for (int d = 32; d; d >>= 1) s += __shfl_xor(s, d);
  if (lane == 0) o[row] = fmaxf(sqrtf(s), 1e-12f);
}

// ---------------- fp32 -> hi/lo planes (bridge accumulator) ----------------
__global__ __launch_bounds__(256) void cvt_hl(
    const float* __restrict__ in, h16* __restrict__ out) {
  size_t e = ((size_t)blockIdx.x * 256 + threadIdx.x) * 4;
  float4 v = *(const float4*)(in + e);
  float vv[4] = {v.x, v.y, v.z, v.w};
  h4 hv, lv;
#pragma unroll
  for (int i = 0; i < 4; ++i) { h16 hi, lo; split_hl(vv[i], hi, lo); hv[i] = hi; lv[i] = lo; }
  *(h4*)(out + e) = hv;
  *(h4*)(out + BANDF + e) = lv;
}

// ---------------- Unified NT MFMA GEMM, fp16x3 split --------------------
// C[M,N] = A[M,K=256] * B[N,K=256]^T via K'=768 (3 segments x 256).
// A/B given as hi plane ptr; lo plane at +aplane/+bplane elements.
// SIM mode: grid.z = batch (A,B advance 2048*256 per batch).
template <int BM, int BN, int WM, int WN, int MODE>
__global__ __launch_bounds__((BM / WM) * (BN / WN) * 64) void mf_gemm(
    const h16* __restrict__ Ap, const h16* __restrict__ Bp,
    long aplane, long bplane,
    const float* __restrict__ bias, float* __restrict__ Cf,
    h16* __restrict__ Chl, long cplane,
    const float* __restrict__ qn, const float* __restrict__ kn,
    const float* __restrict__ temps, int tix, float alpha) {
  constexpr int NW = (BM / WM) * (BN / WN);
  constexpr int NT = NW * 64;
  constexpr int MI = WM / 16, NI = WN / 16;
  constexpr int LA = (BM * 32) / (NT * 8);
  constexpr int LB = (BN * 32) / (NT * 8);
  static_assert(LA >= 1 && LB >= 1, "staging split");
  __shared__ h16 As[BM][40];   // rows padded to 80B: <=2-way bank aliasing
  __shared__ h16 Bs[BN][40];
  const int tid = threadIdx.x;
  const int lane = tid & 63, wid = tid >> 6;
  constexpr int NWC = BN / WN;
  const int wr = wid / NWC, wc = wid % NWC;
  const int bz = blockIdx.z;
  const int row0 = blockIdx.y * BM, col0 = blockIdx.x * BN;

  const h16* Ah = Ap + (size_t)bz * (Tv * Dv);
  const h16* Al = Ah + aplane;
  const h16* Bh = Bp + (size_t)bz * (Tv * Dv);
  const h16* Bl = Bh + bplane;
  const h16 S9 = (h16)0.001953125f;  // 2^-9 exact
  const h16 ONE = (h16)1.0f;

  f4 acc[MI][NI];
#pragma unroll
  for (int mi = 0; mi < MI; ++mi)
#pragma unroll
    for (int ni = 0; ni < NI; ++ni) acc[mi][ni] = (f4){0.f, 0.f, 0.f, 0.f};

  h8 pa[LA], pb[LB];

  auto stage_load = [&](int s) {
    int seg = s >> 3, k0 = (s & 7) * 32;
    const h16 *ab, *bb; h16 as_, bs_;
    if (seg == 0)      { ab = Ah; bb = Bh; as_ = ONE; bs_ = ONE; }
    else if (seg == 1) { ab = Ah; bb = Bl; as_ = S9;  bs_ = ONE; }
    else               { ab = Al; bb = Bh; as_ = ONE; bs_ = S9;  }
#pragma unroll
    for (int j = 0; j < LA; ++j) {
      int idx = tid + j * NT, r = idx >> 2, g = idx & 3;
      h8 v = *(const h8*)(ab + (size_t)(row0 + r) * Dv + k0 + g * 8);
      v *= as_;
      pa[j] = v;
    }
#pragma unroll
    for (int j = 0; j < LB; ++j) {
      int idx = tid + j * NT, r = idx >> 2, g = idx & 3;
      h8 v = *(const h8*)(bb + (size_t)(col0 + r) * Dv + k0 + g * 8);
      v *= bs_;
      pb[j] = v;
    }
  };
  auto stage_write = [&]() {
#pragma unroll
    for (int j = 0; j < LA; ++j) {
      int idx = tid + j * NT, r = idx >> 2, g = idx & 3;
      *(h8*)&As[r][g * 8] = pa[j];
    }
#pragma unroll
    for (int j = 0; j < LB; ++j) {
      int idx = tid + j * NT, r = idx >> 2, g = idx & 3;
      *(h8*)&Bs[r][g * 8] = pb[j];
    }
  };
  auto compute = [&]() {
    h8 af[MI], bf[NI];
#pragma unroll
    for (int mi = 0; mi < MI; ++mi)
      af[mi] = *(const h8*)&As[wr * WM + mi * 16 + (lane & 15)][(lane >> 4) * 8];
#pragma unroll
    for (int ni = 0; ni < NI; ++ni)
      bf[ni] = *(const h8*)&Bs[wc * WN + ni * 16 + (lane & 15)][(lane >> 4) * 8];
#pragma unroll
    for (int mi = 0; mi < MI; ++mi)
#pragma unroll
      for (int ni = 0; ni < NI; ++ni)
        acc[mi][ni] = __builtin_amdgcn_mfma_f32_16x16x32_f16(af[mi], bf[ni],
                                                             acc[mi][ni], 0, 0, 0);
  };

  stage_load(0);
  stage_write();
  __syncthreads();
  for (int s = 0; s < 24; ++s) {
    bool more = (s + 1 < 24);
    if (more) stage_load(s + 1);   // global loads overlap compute
    compute();
    __syncthreads();
    if (more) { stage_write(); __syncthreads(); }
  }

  if constexpr (MODE == 0) {  // SIM epilogue
    float temp = temps[tix];
    float cinv[NI];
#pragma unroll
    for (int ni = 0; ni < NI; ++ni)
      cinv[ni] = 1.0f / kn[bz * Tv + col0 + wc * WN + ni * 16 + (lane & 15)];
#pragma unroll
    for (int mi = 0; mi < MI; ++mi)
#pragma unroll
      for (int r = 0; r < 4; ++r) {
        int grow = row0 + wr * WM + mi * 16 + (lane >> 4) * 4 + r;
        float rinv = 1.0f / (qn[bz * Tv + grow] * temp);
        size_t ro = ((size_t)bz * Tv + grow) * (size_t)Tv;
#pragma unroll
        for (int ni = 0; ni < NI; ++ni) {
          int gcol = col0 + wc * WN + ni * 16 + (lane & 15);
          Cf[ro + gcol] = acc[mi][ni][r] * rinv * cinv[ni];
        }
      }
  } else {  // PROJ epilogues
    float bj[NI];
#pragma unroll
    for (int ni = 0; ni < NI; ++ni)
      bj[ni] = bias[col0 + wc * WN + ni * 16 + (lane & 15)];
#pragma unroll
    for (int mi = 0; mi < MI; ++mi)
#pragma unroll
      for (int r = 0; r < 4; ++r) {
        int grow = row0 + wr * WM + mi * 16 + (lane >> 4) * 4 + r;
        size_t ro = (size_t)grow * Dv;
#pragma unroll
        for (int ni = 0; ni < NI; ++ni) {
          int gcol = col0 + wc * WN + ni * 16 + (lane & 15);
          float y = alpha * acc[mi][ni][r] + bj[ni];
          if constexpr (MODE == 1) {
            Cf[ro + gcol] = y;
          } else if constexpr (MODE == 2) {
            h16 hi, lo; split_hl(y, hi, lo);
            Chl[ro + gcol] = hi;
            Chl[cplane + ro + gcol] = lo;
          } else {
            Cf[ro + gcol] += y;
          }
        }
      }
  }
}

// ---------------- Fused top-16 + softmax + weighted V gather ----------------
// One WAVE per row; u64 sortable keys (value<<32 | (2047-col)); no LDS/barriers.
// HL=1: write attention output as hi/lo planes; HL=0: accumulate fp32.
template <int HL>
__global__ __launch_bounds__(256) void topk_gather(
    const float* __restrict__ S, const float* __restrict__ V,
    float* __restrict__ outf, h16* __restrict__ outh) {
  const int lane = threadIdx.x & 63;
  const int wid = threadIdx.x >> 6;
  const int r = blockIdx.x * 4 + wid;  // 0..8191
  const float* srow = S + (size_t)r * Tv;

  unsigned long long key[32];
#pragma unroll
  for (int j = 0; j < 8; ++j) {
    float4 v = *(const float4*)(srow + j * 256 + lane * 4);
    float vv[4] = {v.x, v.y, v.z, v.w};
#pragma unroll
    for (int c = 0; c < 4; ++c) {
      unsigned u = __float_as_uint(vv[c]);
      unsigned su = u ^ ((unsigned)(((int)u) >> 31) | 0x80000000u);
      int col = j * 256 + lane * 4 + c;
      key[j * 4 + c] = ((unsigned long long)su << 32) | (unsigned)(2047 - col);
    }
  }
  unsigned long long best = key[0];
#pragma unroll
  for (int s2 = 1; s2 < 32; ++s2) best = key[s2] > best ? key[s2] : best;

  unsigned long long wkey[16];
#pragma unroll
  for (int it = 0; it < 16; ++it) {
    unsigned long long m = best;
#pragma unroll
    for (int d = 32; d; d >>= 1) {
      unsigned long long o = __shfl_xor(m, d);
      m = o > m ? o : m;
    }
    wkey[it] = m;
    if (best == m) {
      unsigned long long nb = 0ull;
#pragma unroll
      for (int s2 = 0; s2 < 32; ++s2) {
        unsigned long long k2 = key[s2] < m ? key[s2] : 0ull;
        nb = k2 > nb ? k2 : nb;
      }
      best = nb;
    }
  }

  float w[16];
#pragma unroll
  for (int it = 0; it < 16; ++it) {
    unsigned su = (unsigned)(wkey[it] >> 32);
    unsigned m2 = (unsigned)((~(int)su) >> 31) | 0x80000000u;
    w[it] = __uint_as_float(su ^ m2);
  }
  float ssum = 0.f;
#pragma unroll
  for (int it = 0; it < 16; ++it) {
    w[it] = __expf(w[it] - w[0]);
    ssum += w[it];
  }
  const float inv = 1.0f / ssum;

  const float* Vb = V + ((size_t)(r >> 11) << 11) * Dv;
  float4 acc = {0.f, 0.f, 0.f, 0.f};
#pragma unroll
  for (int it = 0; it < 16; ++it) {
    int col = 2047 - (int)(wkey[it] & 0x7FFu);
    float4 vv = *(const float4*)(Vb + (size_t)col * Dv + lane * 4);
    acc.x += w[it] * vv.x;
    acc.y += w[it] * vv.y;
    acc.z += w[it] * vv.z;
    acc.w += w[it] * vv.w;
  }
  acc.x *= inv; acc.y *= inv; acc.z *= inv; acc.w *= inv;

  if constexpr (HL) {
    float vv[4] = {acc.x, acc.y, acc.z, acc.w};
    h4 hv, lv;
#pragma unroll
    for (int i = 0; i < 4; ++i) { h16 hi, lo; split_hl(vv[i], hi, lo); hv[i] = hi; lv[i] = lo; }
    h16* op = outh + (size_t)r * Dv + lane * 4;
    *(h4*)op = hv;
    *(h4*)(op + BANDF) = lv;
  } else {
    float* op = outf + (size_t)r * Dv + lane * 4;
    float4 p = *(const float4*)op;
    acc.x += p.x; acc.y += p.y; acc.z += p.z; acc.w += p.w;
    *(float4*)op = acc;
  }
}

extern "C" void kernel_launch(void* const* d_in, const int* in_sizes, int n_in,
                              void* d_out, int out_size, void* d_ws, size_t ws_size,
                              hipStream_t stream) {
  const float* bands = (const float*)d_in[0];
  const float* pair_qW = (const float*)d_in[1];
  const float* pair_qb = (const float*)d_in[2];
  const float* pair_kW = (const float*)d_in[3];
  const float* pair_kb = (const float*)d_in[4];
  const float* pair_vW = (const float*)d_in[5];
  const float* pair_vb = (const float*)d_in[6];
  const float* pair_oW = (const float*)d_in[7];
  const float* pair_ob = (const float*)d_in[8];
  const float* bridge_qW = (const float*)d_in[9];
  const float* bridge_qb = (const float*)d_in[10];
  const float* bridge_kW = (const float*)d_in[11];
  const float* bridge_kb = (const float*)d_in[12];
  const float* bridge_vW = (const float*)d_in[13];
  const float* bridge_vb = (const float*)d_in[14];
  const float* bridge_oW = (const float*)d_in[15];
  const float* bridge_ob = (const float*)d_in[16];
  const float* temps = (const float*)d_in[17];
  const float* ln_g = (const float*)d_in[18];
  const float* ln_b = (const float*)d_in[19];

  float* out = (float*)d_out;
  float* ws = (float*)d_ws;

  // ---- workspace layout (~178 MB) ----
  float* simb = ws;                                   // 16,777,216 f
  float* vbuf = simb + (size_t)Bv * Tv * Tv;          // 2,097,152 f
  float* accb = vbuf + BANDF;                         // 2,097,152 f
  float* qn = accb + BANDF;                           // 8192
  float* kn = qn + ROWS;                              // 8192
  h16* nhl = (h16*)(kn + ROWS);                       // 7 * 2*BANDF halves
  h16* qhl = nhl + (size_t)NBv * 2 * BANDF;           // 2*BANDF (also bridge q)
  h16* khl = qhl + 2 * BANDF;                         // 2*BANDF
  h16* whl = khl + 2 * BANDF;                         // 2*BANDF (also accb_hl)
  h16* wt = whl + 2 * BANDF;                          // 38*131072 halves

  static const int SRC[6] = {0, 6, 1, 5, 2, 4};
  static const int DST[6] = {6, 0, 5, 1, 4, 2};
  static const int OTHERS[6] = {0, 1, 2, 4, 5, 6};

  const long PL = (long)BANDF;   // operand plane stride (elements)
  const long WPL = 65536;        // weight plane stride

  auto NHL = [&](int band) { return nhl + (size_t)band * 2 * BANDF; };
  auto WT = [&](int m) { return wt + (size_t)m * 131072; };

  hipMemcpyAsync(out, bands, sizeof(float) * NBv * BANDF,
                 hipMemcpyDeviceToDevice, stream);
  ln_hl<<<NBv * ROWS / 4, 256, 0, stream>>>(bands, ln_g, ln_b, nhl);
  wtrans_all<<<38 * 64, 256, 0, stream>>>(pair_qW, pair_kW, pair_vW, pair_oW,
                                          bridge_kW, bridge_vW, bridge_qW,
                                          bridge_oW, wt);

  const dim3 pg(Dv / 64, ROWS / 64, 1);      // (4,128) proj
  const dim3 sg(Tv / 128, Tv / 128, Bv);     // (16,16,4) sim

  // ---- pair attentions ----
  for (int p = 0; p < 6; ++p) {
    int src = SRC[p], dst = DST[p];
    mf_gemm<64, 64, 32, 32, 2><<<pg, 256, 0, stream>>>(
        NHL(src), WT(p), PL, WPL, pair_qb + p * 256, nullptr, qhl, PL,
        nullptr, nullptr, nullptr, 0, 1.f);
    mf_gemm<64, 64, 32, 32, 2><<<pg, 256, 0, stream>>>(
        NHL(dst), WT(6 + p), PL, WPL, pair_kb + p * 256, nullptr, khl, PL,
        nullptr, nullptr, nullptr, 0, 1.f);
    mf_gemm<64, 64, 32, 32, 1><<<pg, 256, 0, stream>>>(
        NHL(dst), WT(12 + p), PL, WPL, pair_vb + p * 256, vbuf, nullptr, 0,
        nullptr, nullptr, nullptr, 0, 1.f);
    rownorm_hl<<<dim3(ROWS / 4, 2), 256, 0, stream>>>(qhl, qn, khl, kn);
    mf_gemm<128, 128, 64, 64, 0><<<sg, 256, 0, stream>>>(
        qhl, khl, PL, PL, nullptr, simb, nullptr, 0, qn, kn, temps, p, 1.f);
    topk_gather<1><<<ROWS / 4, 256, 0, stream>>>(simb, vbuf, nullptr, whl);
    mf_gemm<64, 64, 32, 32, 3><<<pg, 256, 0, stream>>>(
        whl, WT(18 + p), PL, WPL, pair_ob + p * 256, out + (size_t)src * BANDF,
        nullptr, 0, nullptr, nullptr, nullptr, 0, 1.f);
  }

  // ---- bridge ----
  mf_gemm<64, 64, 32, 32, 2><<<pg, 256, 0, stream>>>(
      NHL(3), WT(36), PL, WPL, bridge_qb, nullptr, qhl, PL,
      nullptr, nullptr, nullptr, 0, 1.f);
  rownorm_hl<<<dim3(ROWS / 4, 1), 256, 0, stream>>>(qhl, qn, qhl, qn);
  hipMemsetAsync(accb, 0, sizeof(float) * BANDF, stream);
  for (int i = 0; i < 6; ++i) {
    int o = OTHERS[i];
    mf_gemm<64, 64, 32, 32, 2><<<pg, 256, 0, stream>>>(
        NHL(o), WT(24 + i), PL, WPL, bridge_kb + i * 256, nullptr, khl, PL,
        nullptr, nullptr, nullptr, 0, 1.f);
    mf_gemm<64, 64, 32, 32, 1><<<pg, 256, 0, stream>>>(
        NHL(o), WT(30 + i), PL, WPL, bridge_vb + i * 256, vbuf, nullptr, 0,
        nullptr, nullptr, nullptr, 0, 1.f);
    rownorm_hl<<<dim3(ROWS / 4, 1), 256, 0, stream>>>(khl, kn, khl, kn);
    mf_gemm<128, 128, 64, 64, 0><<<sg, 256, 0, stream>>>(
        qhl, khl, PL, PL, nullptr, simb, nullptr, 0, qn, kn, temps, 6, 1.f);
    topk_gather<0><<<ROWS / 4, 256, 0, stream>>>(simb, vbuf, accb, nullptr);
  }
  cvt_hl<<<ROWS * Dv / 1024, 256, 0, stream>>>(accb, whl);
  mf_gemm<64, 64, 32, 32, 3><<<pg, 256, 0, stream>>>(
      whl, WT(37), PL, WPL, bridge_ob, out + 3 * BANDF, nullptr, 0,
      nullptr, nullptr, nullptr, 0, 1.0f / 6.0f);
}